// Round 10
// baseline (203.795 us; speedup 1.0000x reference)
//
#include <hip/hip_runtime.h>

typedef unsigned short u16;
typedef unsigned int   u32;
typedef unsigned long long u64;

#define NB     20000   // batch of target nodes
#define SNB    25      // sampled neighbors (padded)
#define FEAT   256
#define K2     512     // 2*FEAT (concat dim)
#define OUTF   256

// DTYPE (settled by execution evidence, rounds 2-8): feats/w0/w1/out = FLOAT32.
// d_ws layout (bytes):
//   [0]           combined bf16 [20000][512] = 20,480,000 B  (MFMA A operand)
//   [20,480,000]  w1 as bf16    [256][512]   =    262,144 B  (MFMA B operand)
#define WS_W1_OFF (NB * K2 * 2)

__device__ __forceinline__ u32 f2bf(float f) {
  union { u32 i; float f; } x; x.f = f;
  return (x.i + 0x7fffu + ((x.i >> 16) & 1u)) >> 16;  // RNE
}
__device__ __forceinline__ u32 pack2(float a, float b) {
  return f2bf(a) | (f2bf(b) << 16);
}

// ---------------------------------------------------------------------------
// w1 f32 -> bf16 (131072 elements).
// ---------------------------------------------------------------------------
__global__ __launch_bounds__(256) void convw_kernel(
    const float* __restrict__ w_raw, u16* __restrict__ w_bf) {
  const int i = blockIdx.x * 256 + threadIdx.x;
  w_bf[i] = (u16)f2bf(w_raw[i]);
}

// ---------------------------------------------------------------------------
// Aggregation: combined[b,0:256] = feats[nodes[b]] (bf16-rounded);
//              combined[b,256:512] = mean(feats[samp_neighs[b,:len]]).
// One wave per node (4 waves/block); lane covers 4 floats (16 B) of the row.
// Memory-system bound (r8: 137 MB HBM fetch, 2.7 TB/s, VALU 11%). combined
// writes are nontemporal (u64-packed: the builtin rejects HIP_vector_type*)
// so the 20 MB streaming output doesn't evict feats rows from L2/L3.
// ---------------------------------------------------------------------------
__global__ __launch_bounds__(256) void agg_kernel(
    const float* __restrict__ feats, const int* __restrict__ nodes,
    const int* __restrict__ neighs, const int* __restrict__ lens,
    u16* __restrict__ combined) {
  const int b    = blockIdx.x * 4 + (threadIdx.x >> 6);  // node id
  const int lane = threadIdx.x & 63;

  const int self = nodes[b];
  const int len  = lens[b];   // guaranteed >= 1
  int myidx = (lane < SNB) ? neighs[b * SNB + lane] : 0;

  const float4 sv = ((const float4*)(feats + (size_t)self * FEAT))[lane];

  float4 a0 = {0.f, 0.f, 0.f, 0.f}, a1 = a0, a2 = a0, a3 = a0;
  int s = 0;
  for (; s + 4 <= len; s += 4) {
    const int i0 = __shfl(myidx, s);
    const int i1 = __shfl(myidx, s + 1);
    const int i2 = __shfl(myidx, s + 2);
    const int i3 = __shfl(myidx, s + 3);
    const float4 v0 = ((const float4*)(feats + (size_t)i0 * FEAT))[lane];
    const float4 v1 = ((const float4*)(feats + (size_t)i1 * FEAT))[lane];
    const float4 v2 = ((const float4*)(feats + (size_t)i2 * FEAT))[lane];
    const float4 v3 = ((const float4*)(feats + (size_t)i3 * FEAT))[lane];
    a0.x += v0.x; a0.y += v0.y; a0.z += v0.z; a0.w += v0.w;
    a1.x += v1.x; a1.y += v1.y; a1.z += v1.z; a1.w += v1.w;
    a2.x += v2.x; a2.y += v2.y; a2.z += v2.z; a2.w += v2.w;
    a3.x += v3.x; a3.y += v3.y; a3.z += v3.z; a3.w += v3.w;
  }
  for (; s < len; ++s) {
    const int i0 = __shfl(myidx, s);
    const float4 v0 = ((const float4*)(feats + (size_t)i0 * FEAT))[lane];
    a0.x += v0.x; a0.y += v0.y; a0.z += v0.z; a0.w += v0.w;
  }
  const float inv = 1.f / (float)len;
  const float m0 = (a0.x + a1.x + a2.x + a3.x) * inv;
  const float m1 = (a0.y + a1.y + a2.y + a3.y) * inv;
  const float m2 = (a0.z + a1.z + a2.z + a3.z) * inv;
  const float m3 = (a0.w + a1.w + a2.w + a3.w) * inv;

  u64* crow = (u64*)(combined + (size_t)b * K2);
  const u64 pe = (u64)pack2(sv.x, sv.y) | ((u64)pack2(sv.z, sv.w) << 32);
  __builtin_nontemporal_store(pe, &crow[lane]);
  const u64 pm = (u64)pack2(m0, m1) | ((u64)pack2(m2, m3) << 32);
  __builtin_nontemporal_store(pm, &crow[64 + lane]);
}

// ---------------------------------------------------------------------------
// GEMM: out[M,256] = relu(combined[M,512] @ w1bf[256,512]^T), f32 out.
// BM=64, BN=128 -> grid 313x2 = 626 blocks (2.45/CU vs r8's 1.23/CU ->
// block-wave tail utilization 61% -> 82%). 4 waves in 2x2; wave tile 32x64 =
// 2x4 MFMA 16x16x32 bf16 (short8 fragments, proven in r5/r8 builds).
// uint4->LDS staging, +8 row pad (2-way bank aliasing only, free per m136).
// ---------------------------------------------------------------------------
typedef __attribute__((ext_vector_type(8))) short short8;
typedef __attribute__((ext_vector_type(4))) float f32x4;

#define BM 64
#define BN 128
#define BK 32
#define LDST 40   // 32 + 8 pad elements

__global__ __launch_bounds__(256) void gemm_kernel(
    const u16* __restrict__ A,   // [M, 512] combined bf16 (K-contiguous)
    const u16* __restrict__ W,   // [256, 512] w1 bf16 (K-contiguous)
    float* __restrict__ C,       // [M, 256] f32
    int M) {
  __shared__ u16 As[BM * LDST];
  __shared__ u16 Bs[BN * LDST];

  const int tid  = threadIdx.x;
  const int wave = tid >> 6;
  const int lane = tid & 63;
  const int m0 = blockIdx.x * BM;
  const int n0 = blockIdx.y * BN;

  const int wr = (wave >> 1) * 32;  // wave sub-tile row origin (0 or 32)
  const int wc = (wave & 1) * 64;   // wave sub-tile col origin (0 or 64)

  f32x4 acc[2][4] = {};

  const int r16 = lane & 15;
  const int kq  = (lane >> 4) * 8;   // k-offset of this lane's quad

  const int srow = tid >> 2;         // staging row 0..63
  const int skc  = tid & 3;          // 16-B chunk within 32-elem k-slice

  for (int k0 = 0; k0 < K2; k0 += BK) {
    {  // A-tile: 64 rows x 4 chunks = 256 chunks, one per thread
      int ar = m0 + srow; if (ar >= M) ar = M - 1;  // clamp; predicated out
      const uint4 va = ((const uint4*)(A + (size_t)ar * K2 + k0))[skc];
      *(uint4*)&As[srow * LDST + skc * 8] = va;
    }
#pragma unroll
    for (int i = 0; i < 2; ++i) {  // B-tile: 128 rows x 4 chunks = 2/thread
      const int row = i * 64 + srow;
      const uint4 vb = ((const uint4*)(W + (size_t)(n0 + row) * K2 + k0))[skc];
      *(uint4*)&Bs[row * LDST + skc * 8] = vb;
    }
    __syncthreads();

    short8 af[2], bf[4];
#pragma unroll
    for (int i = 0; i < 2; ++i)
      af[i] = *(const short8*)&As[(wr + i * 16 + r16) * LDST + kq];
#pragma unroll
    for (int j = 0; j < 4; ++j)
      bf[j] = *(const short8*)&Bs[(wc + j * 16 + r16) * LDST + kq];

#pragma unroll
    for (int i = 0; i < 2; ++i)
#pragma unroll
      for (int j = 0; j < 4; ++j)
        acc[i][j] = __builtin_amdgcn_mfma_f32_16x16x32_bf16(af[i], bf[j],
                                                            acc[i][j], 0, 0, 0);
    __syncthreads();
  }

  // Epilogue: C/D layout col = lane&15, row = (lane>>4)*4 + reg  [m89]
#pragma unroll
  for (int i = 0; i < 2; ++i) {
#pragma unroll
    for (int r = 0; r < 4; ++r) {
      const int row = m0 + wr + i * 16 + (lane >> 4) * 4 + r;
      if (row < M) {
#pragma unroll
        for (int j = 0; j < 4; ++j) {
          const int col = n0 + wc + j * 16 + (lane & 15);
          float v = acc[i][j][r];
          C[(size_t)row * OUTF + col] = v > 0.f ? v : 0.f;
        }
      }
    }
  }
}

// ---------------------------------------------------------------------------
extern "C" void kernel_launch(void* const* d_in, const int* in_sizes, int n_in,
                              void* d_out, int out_size, void* d_ws, size_t ws_size,
                              hipStream_t stream) {
  const float* feats = (const float*)d_in[0];  // [100000, 256] f32
  const int* nodes   = (const int*)d_in[1];    // [20000]
  const int* neighs  = (const int*)d_in[2];    // [20000, 25]
  const int* lens    = (const int*)d_in[3];    // [20000]
  // d_in[4] = w0 — dead: layer-0 output is discarded by the reference loop.
  const float* w1    = (const float*)d_in[5];  // [256, 512] f32
  float* out = (float*)d_out;                  // [20000, 256] f32

  char* ws = (char*)d_ws;
  u16* combined = (u16*)ws;                    // [20000, 512] bf16
  u16* w1bf     = (u16*)(ws + WS_W1_OFF);      // [256, 512] bf16

  convw_kernel<<<512, 256, 0, stream>>>(w1, w1bf);
  agg_kernel<<<NB / 4, 256, 0, stream>>>(feats, nodes, neighs, lens, combined);

  dim3 grid((NB + BM - 1) / BM, OUTF / BN);    // 313 x 2
  gemm_kernel<<<grid, 256, 0, stream>>>(combined, w1bf, out, NB);
}